// Round 3
// baseline (34296.948 us; speedup 1.0000x reference)
//
#include <hip/hip_runtime.h>
#include <stdint.h>

// ---------------- constants ----------------
#define T_STEPS 1000
#define SDIM    128
#define ADIM    32
#define HID     256
#define TDIM    16
#define KPX     40                     // padded K stride for x tile (32 used)
#define KPH     264                    // padded K stride for hidden tiles (256 used)

typedef __attribute__((ext_vector_type(8))) short short8;   // 8 bf16 (4 VGPRs)
typedef __attribute__((ext_vector_type(4))) float f32x4;    // MFMA accumulator

#define MFMA(A, B, C) __builtin_amdgcn_mfma_f32_16x16x32_bf16((A), (B), (C), 0, 0, 0)

// ---------------- bf16 helpers (RNE) ----------------
__device__ __forceinline__ unsigned short f2bf(float f) {
  uint32_t u = __float_as_uint(f);
  u = u + 0x7FFFu + ((u >> 16) & 1u);
  return (unsigned short)(u >> 16);
}
__device__ __forceinline__ float bf2f(unsigned short h) {
  return __uint_as_float(((uint32_t)h) << 16);
}

// ---------------- threefry2x32 (exact JAX semantics) ----------------
__device__ __forceinline__ uint32_t rotl32(uint32_t v, int d) {
  return (v << d) | (v >> (32 - d));
}
__device__ __forceinline__ void threefry2x32(uint32_t k0, uint32_t k1,
                                             uint32_t x0, uint32_t x1,
                                             uint32_t& o0, uint32_t& o1) {
  uint32_t ks0 = k0, ks1 = k1, ks2 = k0 ^ k1 ^ 0x1BD11BDAu;
  x0 += ks0; x1 += ks1;
#define TF_ROUND(r) { x0 += x1; x1 = rotl32(x1, (r)); x1 ^= x0; }
  TF_ROUND(13) TF_ROUND(15) TF_ROUND(26) TF_ROUND(6)
  x0 += ks1; x1 += ks2 + 1u;
  TF_ROUND(17) TF_ROUND(29) TF_ROUND(16) TF_ROUND(24)
  x0 += ks2; x1 += ks0 + 2u;
  TF_ROUND(13) TF_ROUND(15) TF_ROUND(26) TF_ROUND(6)
  x0 += ks0; x1 += ks1 + 3u;
  TF_ROUND(17) TF_ROUND(29) TF_ROUND(16) TF_ROUND(24)
  x0 += ks1; x1 += ks2 + 4u;
  TF_ROUND(13) TF_ROUND(15) TF_ROUND(26) TF_ROUND(6)
  x0 += ks2; x1 += ks0 + 5u;
#undef TF_ROUND
  o0 = x0; o1 = x1;
}
__device__ __forceinline__ uint32_t random_bits32_partitionable(uint32_t k0, uint32_t k1,
                                                               uint32_t j) {
  uint32_t o0, o1;
  threefry2x32(k0, k1, 0u, j, o0, o1);
  return o0 ^ o1;
}

// ---------------- XLA ErfInv (f32 Giles polynomial) ----------------
__device__ __forceinline__ float erfinv_f32(float x) {
  float w = -log1pf(-(x * x));
  float p;
  if (w < 5.0f) {
    w = w - 2.5f;
    p = 2.81022636e-08f;
    p = fmaf(p, w, 3.43273939e-07f);
    p = fmaf(p, w, -3.5233877e-06f);
    p = fmaf(p, w, -4.39150654e-06f);
    p = fmaf(p, w, 0.00021858087f);
    p = fmaf(p, w, -0.00125372503f);
    p = fmaf(p, w, -0.00417768164f);
    p = fmaf(p, w, 0.246640727f);
    p = fmaf(p, w, 1.50140941f);
  } else {
    w = sqrtf(w) - 3.0f;
    p = -0.000200214257f;
    p = fmaf(p, w, 0.000100950558f);
    p = fmaf(p, w, 0.00134934322f);
    p = fmaf(p, w, -0.00367342844f);
    p = fmaf(p, w, 0.00573950773f);
    p = fmaf(p, w, -0.0076224613f);
    p = fmaf(p, w, 0.00943887047f);
    p = fmaf(p, w, 1.00167406f);
    p = fmaf(p, w, 2.83297682f);
  }
  return p * x;
}
__device__ __forceinline__ float bits_to_normal(uint32_t bits) {
  float f = __uint_as_float((bits >> 9) | 0x3F800000u) - 1.0f;   // [0,1)
  float u = f * 2.0f + (-0.99999994f);
  u = fmaxf(-0.99999994f, u);
  return 1.41421356237309515f * erfinv_f32(u);   // sqrt(2) as f32
}

// mish(x) = x * t/(t+2), t = e^x (e^x + 2)
__device__ __forceinline__ float mish_f(float x) {
  float e = expf(fminf(x, 20.0f));
  float t = fmaf(e, e, 2.0f * e);
  return x * (t / (t + 2.0f));
}

// ---------------- precompute: tf_all[1000][16], coefs[5][1000], keys[1000][2] -----
__global__ __launch_bounds__(64)
void precompute_kernel(const float* __restrict__ w_t1, const float* __restrict__ b_t1,
                       const float* __restrict__ w_t2, const float* __restrict__ b_t2,
                       float* __restrict__ tf_all, float* __restrict__ coefs,
                       uint32_t* __restrict__ keys) {
  const int i = blockIdx.x;
  const int j = threadIdx.x;
  const float tv = (float)i;
  __shared__ float hid[32];
  const float CF = (float)(-1.3157629102823120);  // -log(10000)/7
  if (j < 32) {
    float acc = b_t1[j];
#pragma unroll
    for (int k = 0; k < 16; ++k) {
      int kf = (k < 8) ? k : (k - 8);
      float fr = expf((float)kf * CF);
      float ang = tv * fr;
      float te = (k < 8) ? sinf(ang) : cosf(ang);
      acc = fmaf(te, w_t1[k * 32 + j], acc);
    }
    hid[j] = mish_f(acc);
  }
  __syncthreads();
  if (j < 16) {
    float acc = b_t2[j];
#pragma unroll
    for (int k2 = 0; k2 < 32; ++k2) acc = fmaf(hid[k2], w_t2[k2 * 16 + j], acc);
    tf_all[i * TDIM + j] = acc;
  }
  if (j == 0) {
    double t = (double)(i + 1);
    double ac  = exp(-0.1 * t / 1000.0 - 4.95 * t * t / 1.0e6);
    double acp = (i == 0) ? 1.0
        : exp(-0.1 * (t - 1.0) / 1000.0 - 4.95 * (t - 1.0) * (t - 1.0) / 1.0e6);
    double alpha = exp(-0.1 / 1000.0 - 4.95 * (2.0 * t - 1.0) / 1.0e6);
    double beta = 1.0 - alpha;
    double sr   = sqrt(1.0 / ac);
    double srm1 = sqrt(1.0 / ac - 1.0);
    double c1 = beta * sqrt(acp) / (1.0 - ac);
    double c2 = (1.0 - acp) * sqrt(alpha) / (1.0 - ac);
    double pv = beta * (1.0 - acp) / (1.0 - ac);
    double lv = log(fmax(pv, 1.0e-20));
    coefs[0 * T_STEPS + i] = (float)sr;
    coefs[1 * T_STEPS + i] = (float)srm1;
    coefs[2 * T_STEPS + i] = (float)c1;
    coefs[3 * T_STEPS + i] = (float)c2;
    float lvf = (float)lv;
    coefs[4 * T_STEPS + i] = expf(0.5f * lvf);
    uint32_t o0, o1;
    threefry2x32(0u, 1u, 0u, (uint32_t)i, o0, o1);
    keys[2 * i]     = o0;
    keys[2 * i + 1] = o1;
  }
}

// -------- prep: MFMA B-fragment hi/lo layout + w0tf transpose ---------------------
// frag block of 1024 ushort at F + idx*1024: [0..512) hi plane, [512..1024) lo plane;
// lane l, j=0..7 at l*8+j -> W[rowoff + kt*32+(l>>4)*8+j][nt*16+(l&15)]
// blocks 352..355: w0tf[n][c] = w0[(32+c)*HID + n]  (tf-rows of W0, transposed, f32)
__global__ __launch_bounds__(64)
void prep_frags(const float* __restrict__ w0, const float* __restrict__ w1,
                const float* __restrict__ w2, const float* __restrict__ wf,
                unsigned short* __restrict__ f0x, unsigned short* __restrict__ f0s,
                unsigned short* __restrict__ f1, unsigned short* __restrict__ f2,
                unsigned short* __restrict__ ff, float* __restrict__ w0tf) {
  const int bid = blockIdx.x;   // 0..355
  const int l = threadIdx.x;    // 0..63
  if (bid >= 352) {             // w0tf transpose
    int n = (bid - 352) * 64 + l;
#pragma unroll
    for (int c = 0; c < 16; ++c) w0tf[n * 16 + c] = w0[(32 + c) * HID + n];
    return;
  }
  const float* W; unsigned short* F; int NT, N, idx, rowoff, Kmax;
  if (bid < 16)       { W = w0; F = f0x; NT = 16; N = 256; idx = bid;       rowoff = 0;  Kmax = 32;  }
  else if (bid < 80)  { W = w0; F = f0s; NT = 16; N = 256; idx = bid - 16;  rowoff = 48; Kmax = 128; }
  else if (bid < 208) { W = w1; F = f1;  NT = 16; N = 256; idx = bid - 80;  rowoff = 0;  Kmax = 256; }
  else if (bid < 336) { W = w2; F = f2;  NT = 16; N = 256; idx = bid - 208; rowoff = 0;  Kmax = 256; }
  else                { W = wf; F = ff;  NT = 2;  N = 32;  idx = bid - 336; rowoff = 0;  Kmax = 256; }
  const int kt = idx / NT, nt = idx % NT;
  const int n = nt * 16 + (l & 15);
  const int kbase = kt * 32 + (l >> 4) * 8;
  unsigned short* dst = F + idx * 1024 + l * 8;
#pragma unroll
  for (int j = 0; j < 8; ++j) {
    int k = kbase + j;
    float v = (k < Kmax) ? W[(rowoff + k) * N + n] : 0.0f;
    unsigned short h = f2bf(v);
    dst[j]       = h;
    dst[512 + j] = f2bf(v - bf2f(h));
  }
}

// ---------------- persistent main kernel ------------------------------------------
// Per iter: L0 = 1 kt over x only (state part in persistent sacc regs, tf part via
// per-lane 16-dot bias computed from tf_all/w0tf). F1 register-prefetched during
// previous posterior; F2 issued after L1 MFMAs; ff after L2 MFMAs. All loads drain
// at the following __syncthreads.
__global__ __launch_bounds__(512, 2)
void diffusion_main(const float* __restrict__ state, const float* __restrict__ x_init,
                    const float* __restrict__ b0, const float* __restrict__ b1,
                    const float* __restrict__ b2, const float* __restrict__ bf,
                    const unsigned short* __restrict__ f0x, const unsigned short* __restrict__ f0s,
                    const unsigned short* __restrict__ f1, const unsigned short* __restrict__ f2,
                    const unsigned short* __restrict__ ff,
                    const float* __restrict__ tf_all, const float* __restrict__ w0tf,
                    const float* __restrict__ coefs,
                    const uint32_t* __restrict__ keys, float* __restrict__ out) {
  __shared__ __align__(16) unsigned short a0h[16][KPX], a0l[16][KPX];
  __shared__ __align__(16) unsigned short aAh[16][KPH], aAl[16][KPH];
  __shared__ __align__(16) unsigned short aBh[16][KPH], aBl[16][KPH];
  __shared__ float s_x[16][ADIM];
  __shared__ float s_eps[16][33];

  const int tid = threadIdx.x;          // 0..511
  const int base = blockIdx.x * 8;
  const int l = tid & 63;               // lane
  const int w = tid >> 6;               // wave 0..7
  const int lrow = l & 15;
  const int quad = l >> 4;              // 0..3
  const int nt0 = 2 * w, nt1 = 2 * w + 1;

  // ---- stage x_init (16x32 = 512, one elem/thread) ----
  {
    int r = tid >> 5, d = tid & 31;
    int grow = (r < 8) ? (base + r) : (2048 + base + r - 8);
    float v = x_init[grow * ADIM + d];
    s_x[r][d] = v;
    unsigned short h = f2bf(v);
    a0h[r][d] = h; a0l[r][d] = f2bf(v - bf2f(h));
  }
  // ---- stage state into aA cols 0..127 (one-time) ----
  for (int idx = tid; idx < 16 * SDIM; idx += 512) {
    int r = idx >> 7, c = idx & 127;
    int grow = (r < 8) ? (base + r) : (2048 + base + r - 8);
    float v = state[grow * SDIM + c];
    unsigned short h = f2bf(v);
    aAh[r][c] = h; aAl[r][c] = f2bf(v - bf2f(h));
  }

  const float b0A = b0[nt0 * 16 + lrow], b0B = b0[nt1 * 16 + lrow];
  const float b1A = b1[nt0 * 16 + lrow], b1B = b1[nt1 * 16 + lrow];
  const float b2A = b2[nt0 * 16 + lrow], b2B = b2[nt1 * 16 + lrow];
  const float bfv = (w < 2) ? bf[w * 16 + lrow] : 0.0f;
  __syncthreads();

  // ---- one-time: sacc = state-part of layer0 (persistent f32 accumulators) ----
  f32x4 sacc0 = {0.f, 0.f, 0.f, 0.f}, sacc1 = {0.f, 0.f, 0.f, 0.f};
  {
    const unsigned short* aH = &aAh[0][0] + lrow * KPH + quad * 8;
    const unsigned short* aL = &aAl[0][0] + lrow * KPH + quad * 8;
#pragma unroll
    for (int kt = 0; kt < 4; ++kt) {
      short8 ah = *reinterpret_cast<const short8*>(aH + kt * 32);
      short8 al = *reinterpret_cast<const short8*>(aL + kt * 32);
      const unsigned short* p0 = f0s + (kt * 16 + nt0) * 1024 + l * 8;
      const unsigned short* p1 = f0s + (kt * 16 + nt1) * 1024 + l * 8;
      short8 bh0 = *reinterpret_cast<const short8*>(p0);
      short8 bl0 = *reinterpret_cast<const short8*>(p0 + 512);
      short8 bh1 = *reinterpret_cast<const short8*>(p1);
      short8 bl1 = *reinterpret_cast<const short8*>(p1 + 512);
      sacc0 = MFMA(ah, bh0, sacc0); sacc1 = MFMA(ah, bh1, sacc1);
      sacc0 = MFMA(al, bh0, sacc0); sacc1 = MFMA(al, bh1, sacc1);
      sacc0 = MFMA(ah, bl0, sacc0); sacc1 = MFMA(ah, bl1, sacc1);
    }
  }

  // ---- persistent loop-invariant x fragments (kt=0 of layer0) ----
  short8 X0h, X0l, X1h, X1l;
  {
    const unsigned short* p0 = f0x + nt0 * 1024 + l * 8;
    const unsigned short* p1 = f0x + nt1 * 1024 + l * 8;
    X0h = *reinterpret_cast<const short8*>(p0);
    X0l = *reinterpret_cast<const short8*>(p0 + 512);
    X1h = *reinterpret_cast<const short8*>(p1);
    X1l = *reinterpret_cast<const short8*>(p1 + 512);
  }

  // ---- per-lane tf-bias dot (16 f32 FMAs per output col) ----
  const float4* wtA = reinterpret_cast<const float4*>(w0tf + (nt0 * 16 + lrow) * 16);
  const float4* wtB = reinterpret_cast<const float4*>(w0tf + (nt1 * 16 + lrow) * 16);
  const float4 wa0 = wtA[0], wa1 = wtA[1], wa2 = wtA[2], wa3 = wtA[3];
  const float4 wb0 = wtB[0], wb1 = wtB[1], wb2 = wtB[2], wb3 = wtB[3];
  float btA, btB;
  auto compute_bt = [&](int tt) {
    const float4* tfr = reinterpret_cast<const float4*>(tf_all + tt * TDIM);
    float4 t0 = tfr[0], t1 = tfr[1], t2 = tfr[2], t3 = tfr[3];
    float a = t0.x * wa0.x; float b = t0.x * wb0.x;
    a = fmaf(t0.y, wa0.y, a); b = fmaf(t0.y, wb0.y, b);
    a = fmaf(t0.z, wa0.z, a); b = fmaf(t0.z, wb0.z, b);
    a = fmaf(t0.w, wa0.w, a); b = fmaf(t0.w, wb0.w, b);
    a = fmaf(t1.x, wa1.x, a); b = fmaf(t1.x, wb1.x, b);
    a = fmaf(t1.y, wa1.y, a); b = fmaf(t1.y, wb1.y, b);
    a = fmaf(t1.z, wa1.z, a); b = fmaf(t1.z, wb1.z, b);
    a = fmaf(t1.w, wa1.w, a); b = fmaf(t1.w, wb1.w, b);
    a = fmaf(t2.x, wa2.x, a); b = fmaf(t2.x, wb2.x, b);
    a = fmaf(t2.y, wa2.y, a); b = fmaf(t2.y, wb2.y, b);
    a = fmaf(t2.z, wa2.z, a); b = fmaf(t2.z, wb2.z, b);
    a = fmaf(t2.w, wa2.w, a); b = fmaf(t2.w, wb2.w, b);
    a = fmaf(t3.x, wa3.x, a); b = fmaf(t3.x, wb3.x, b);
    a = fmaf(t3.y, wa3.y, a); b = fmaf(t3.y, wb3.y, b);
    a = fmaf(t3.z, wa3.z, a); b = fmaf(t3.z, wb3.z, b);
    a = fmaf(t3.w, wa3.w, a); b = fmaf(t3.w, wb3.w, b);
    btA = a; btB = b;
  };
  compute_bt(T_STEPS - 1);

  // ---- F1 register prefetch (reloaded each iter during posterior phase) ----
  short8 F1h0[8], F1l0[8], F1h1[8], F1l1[8];
  auto loadF1 = [&]() {
#pragma unroll
    for (int kt = 0; kt < 8; ++kt) {
      const unsigned short* p0 = f1 + (kt * 16 + nt0) * 1024 + l * 8;
      const unsigned short* p1 = f1 + (kt * 16 + nt1) * 1024 + l * 8;
      F1h0[kt] = *reinterpret_cast<const short8*>(p0);
      F1l0[kt] = *reinterpret_cast<const short8*>(p0 + 512);
      F1h1[kt] = *reinterpret_cast<const short8*>(p1);
      F1l1[kt] = *reinterpret_cast<const short8*>(p1 + 512);
    }
  };
  loadF1();

  // epilogue helper: acc -> mish -> hi/lo LDS tile
  auto epi_store = [&](const f32x4& acc0, const f32x4& acc1, float bA, float bB,
                       unsigned short* dH, unsigned short* dL) {
#pragma unroll
    for (int reg = 0; reg < 4; ++reg) {
      int orow = quad * 4 + reg;
      float v0 = mish_f(acc0[reg] + bA);
      float v1 = mish_f(acc1[reg] + bB);
      unsigned short h0 = f2bf(v0), h1 = f2bf(v1);
      dH[orow * KPH + nt0 * 16 + lrow] = h0;
      dL[orow * KPH + nt0 * 16 + lrow] = f2bf(v0 - bf2f(h0));
      dH[orow * KPH + nt1 * 16 + lrow] = h1;
      dL[orow * KPH + nt1 * 16 + lrow] = f2bf(v1 - bf2f(h1));
    }
  };

  __syncthreads();  // B0: state reads done, F1 drained

  for (int t = T_STEPS - 1; t >= 0; --t) {
    // uniform scalar loads for posterior (hidden under L0..LF)
    float sr  = coefs[0 * T_STEPS + t];
    float srm = coefs[1 * T_STEPS + t];
    float c1  = coefs[2 * T_STEPS + t];
    float c2  = coefs[3 * T_STEPS + t];
    float sig = (t != 0) ? coefs[4 * T_STEPS + t] : 0.0f;
    uint32_t k0 = keys[2 * t], k1 = keys[2 * t + 1];

    // ---- L0: x-part only (1 kt), acc starts from persistent state part ----
    {
      f32x4 acc0 = sacc0, acc1 = sacc1;
      short8 ah = *reinterpret_cast<const short8*>(&a0h[0][0] + lrow * KPX + quad * 8);
      short8 al = *reinterpret_cast<const short8*>(&a0l[0][0] + lrow * KPX + quad * 8);
      acc0 = MFMA(ah, X0h, acc0); acc1 = MFMA(ah, X1h, acc1);
      acc0 = MFMA(al, X0h, acc0); acc1 = MFMA(al, X1h, acc1);
      acc0 = MFMA(ah, X0l, acc0); acc1 = MFMA(ah, X1l, acc1);
      epi_store(acc0, acc1, b0A + btA, b0B + btB, &aAh[0][0], &aAl[0][0]);
    }
    __syncthreads();  // B1: aA ready

    short8 F2h0[8], F2l0[8], F2h1[8], F2l1[8];
    // ---- L1: consume prefetched F1; then issue F2 loads (drain at B2) ----
    {
      f32x4 acc0 = {0.f, 0.f, 0.f, 0.f}, acc1 = {0.f, 0.f, 0.f, 0.f};
      const unsigned short* aH = &aAh[0][0] + lrow * KPH + quad * 8;
      const unsigned short* aL = &aAl[0][0] + lrow * KPH + quad * 8;
#pragma unroll
      for (int kt = 0; kt < 8; ++kt) {
        short8 ah = *reinterpret_cast<const short8*>(aH + kt * 32);
        short8 al = *reinterpret_cast<const short8*>(aL + kt * 32);
        acc0 = MFMA(ah, F1h0[kt], acc0); acc1 = MFMA(ah, F1h1[kt], acc1);
        acc0 = MFMA(al, F1h0[kt], acc0); acc1 = MFMA(al, F1h1[kt], acc1);
        acc0 = MFMA(ah, F1l0[kt], acc0); acc1 = MFMA(ah, F1l1[kt], acc1);
      }
      __builtin_amdgcn_sched_barrier(0);
#pragma unroll
      for (int kt = 0; kt < 8; ++kt) {
        const unsigned short* p0 = f2 + (kt * 16 + nt0) * 1024 + l * 8;
        const unsigned short* p1 = f2 + (kt * 16 + nt1) * 1024 + l * 8;
        F2h0[kt] = *reinterpret_cast<const short8*>(p0);
        F2l0[kt] = *reinterpret_cast<const short8*>(p0 + 512);
        F2h1[kt] = *reinterpret_cast<const short8*>(p1);
        F2l1[kt] = *reinterpret_cast<const short8*>(p1 + 512);
      }
      __builtin_amdgcn_sched_barrier(0);
      epi_store(acc0, acc1, b1A, b1B, &aBh[0][0], &aBl[0][0]);
    }
    __syncthreads();  // B2: aB ready, F2 drained

    short8 Gh[8], Gl[8];  // ff frags (waves 0,1)
    // ---- L2: consume F2; issue ff loads (drain at B3) ----
    {
      f32x4 acc0 = {0.f, 0.f, 0.f, 0.f}, acc1 = {0.f, 0.f, 0.f, 0.f};
      const unsigned short* aH = &aBh[0][0] + lrow * KPH + quad * 8;
      const unsigned short* aL = &aBl[0][0] + lrow * KPH + quad * 8;
#pragma unroll
      for (int kt = 0; kt < 8; ++kt) {
        short8 ah = *reinterpret_cast<const short8*>(aH + kt * 32);
        short8 al = *reinterpret_cast<const short8*>(aL + kt * 32);
        acc0 = MFMA(ah, F2h0[kt], acc0); acc1 = MFMA(ah, F2h1[kt], acc1);
        acc0 = MFMA(al, F2h0[kt], acc0); acc1 = MFMA(al, F2h1[kt], acc1);
        acc0 = MFMA(ah, F2l0[kt], acc0); acc1 = MFMA(ah, F2l1[kt], acc1);
      }
      __builtin_amdgcn_sched_barrier(0);
      if (w < 2) {
#pragma unroll
        for (int kt = 0; kt < 8; ++kt) {
          const unsigned short* p = ff + (kt * 2 + w) * 1024 + l * 8;
          Gh[kt] = *reinterpret_cast<const short8*>(p);
          Gl[kt] = *reinterpret_cast<const short8*>(p + 512);
        }
      }
      __builtin_amdgcn_sched_barrier(0);
      epi_store(acc0, acc1, b2A, b2B, &aAh[0][0], &aAl[0][0]);
    }
    __syncthreads();  // B3: aA(L2 out) ready, ff drained

    // ---- LF: 256->32, waves 0,1 ----
    if (w < 2) {
      f32x4 acc = {0.f, 0.f, 0.f, 0.f};
      const unsigned short* aH = &aAh[0][0] + lrow * KPH + quad * 8;
      const unsigned short* aL = &aAl[0][0] + lrow * KPH + quad * 8;
#pragma unroll
      for (int kt = 0; kt < 8; ++kt) {
        short8 ah = *reinterpret_cast<const short8*>(aH + kt * 32);
        short8 al = *reinterpret_cast<const short8*>(aL + kt * 32);
        acc = MFMA(ah, Gh[kt], acc);
        acc = MFMA(al, Gh[kt], acc);
        acc = MFMA(ah, Gl[kt], acc);
      }
#pragma unroll
      for (int reg = 0; reg < 4; ++reg)
        s_eps[quad * 4 + reg][w * 16 + lrow] = acc[reg] + bfv;
    }
    __syncthreads();  // B4: eps ready

    // ---- posterior update + JAX noise; refresh a0 x tile ----
    {
      int d = tid & 31;
      int r = tid >> 5;
      int grow = (r < 8) ? (base + r) : (2048 + base + r - 8);
      uint32_t jflat = (uint32_t)(grow * ADIM + d);
      float nzv = bits_to_normal(random_bits32_partitionable(k0, k1, jflat));
      float xv = s_x[r][d];
      float eps = s_eps[r][d];
      float x0v = fminf(fmaxf(sr * xv - srm * eps, -1.0f), 1.0f);
      float xn = c1 * x0v + c2 * xv + sig * nzv;
      s_x[r][d] = xn;
      unsigned short h = f2bf(xn);
      a0h[r][d] = h; a0l[r][d] = f2bf(xn - bf2f(h));
    }
    // prefetch next iteration's F1 + tf-bias (latency hides under posterior)
    loadF1();
    compute_bt((t > 0) ? (t - 1) : 0);
    __syncthreads();  // B5: a0 ready for next L0, F1 drained
  }

  // ---- output (same thread wrote s_x[r][d]) ----
  {
    int r = tid >> 5, d = tid & 31;
    int grow = (r < 8) ? (base + r) : (2048 + base + r - 8);
    out[grow * ADIM + d] = fminf(fmaxf(s_x[r][d], -1.0f), 1.0f);
  }
}

// ---------------- launcher ----------------
extern "C" void kernel_launch(void* const* d_in, const int* in_sizes, int n_in,
                              void* d_out, int out_size, void* d_ws, size_t ws_size,
                              hipStream_t stream) {
  const float* state = (const float*)d_in[0];
  const float* x_init = (const float*)d_in[1];
  const float* w_t1 = (const float*)d_in[2];
  const float* b_t1 = (const float*)d_in[3];
  const float* w_t2 = (const float*)d_in[4];
  const float* b_t2 = (const float*)d_in[5];
  const float* w0 = (const float*)d_in[6];
  const float* b0 = (const float*)d_in[7];
  const float* w1 = (const float*)d_in[8];
  const float* b1 = (const float*)d_in[9];
  const float* w2 = (const float*)d_in[10];
  const float* b2 = (const float*)d_in[11];
  const float* wf = (const float*)d_in[12];
  const float* bf = (const float*)d_in[13];
  float* out = (float*)d_out;

  // ws layout (f32 units unless noted), total ~829 KB (< previous 846 KB):
  //   tf_all[16000] | w0tf[4096] | coefs[5000] | keys[2000] u32
  //   | f0x[16K ush] | f0s[64K] | f1[128K] | f2[128K] | ff[16K]
  float* tf_all = (float*)d_ws;
  float* w0tf = tf_all + T_STEPS * TDIM;
  float* coefs = w0tf + HID * TDIM;
  uint32_t* keys = (uint32_t*)(coefs + 5 * T_STEPS);
  unsigned short* f0x = (unsigned short*)(keys + 2 * T_STEPS);
  unsigned short* f0s = f0x + 16 * 1024;
  unsigned short* f1 = f0s + 64 * 1024;
  unsigned short* f2 = f1 + 128 * 1024;
  unsigned short* ff = f2 + 128 * 1024;

  precompute_kernel<<<T_STEPS, 64, 0, stream>>>(w_t1, b_t1, w_t2, b_t2,
                                                tf_all, coefs, keys);
  prep_frags<<<356, 64, 0, stream>>>(w0, w1, w2, wf, f0x, f0s, f1, f2, ff, w0tf);
  diffusion_main<<<256, 512, 0, stream>>>(state, x_init, b0, b1, b2, bf,
                                          f0x, f0s, f1, f2, ff,
                                          tf_all, w0tf, coefs, keys, out);
}

// Round 4
// 19315.143 us; speedup vs baseline: 1.7757x; 1.7757x over previous
//
#include <hip/hip_runtime.h>
#include <stdint.h>

// ---------------- constants ----------------
#define T_STEPS 1000
#define SDIM    128
#define ADIM    32
#define HID     256
#define TDIM    16
#define KPX     40                     // padded K stride for x tile (32 used)
#define KPH     264                    // padded K stride for hidden tiles (256 used)

typedef __attribute__((ext_vector_type(8))) short short8;   // 8 bf16 (4 VGPRs)
typedef __attribute__((ext_vector_type(4))) float f32x4;    // MFMA accumulator

#define MFMA(A, B, C) __builtin_amdgcn_mfma_f32_16x16x32_bf16((A), (B), (C), 0, 0, 0)

// ---------------- bf16 helpers (RNE) ----------------
__device__ __forceinline__ unsigned short f2bf(float f) {
  uint32_t u = __float_as_uint(f);
  u = u + 0x7FFFu + ((u >> 16) & 1u);
  return (unsigned short)(u >> 16);
}
__device__ __forceinline__ float bf2f(unsigned short h) {
  return __uint_as_float(((uint32_t)h) << 16);
}

// ---------------- threefry2x32 (exact JAX semantics) ----------------
__device__ __forceinline__ uint32_t rotl32(uint32_t v, int d) {
  return (v << d) | (v >> (32 - d));
}
__device__ __forceinline__ void threefry2x32(uint32_t k0, uint32_t k1,
                                             uint32_t x0, uint32_t x1,
                                             uint32_t& o0, uint32_t& o1) {
  uint32_t ks0 = k0, ks1 = k1, ks2 = k0 ^ k1 ^ 0x1BD11BDAu;
  x0 += ks0; x1 += ks1;
#define TF_ROUND(r) { x0 += x1; x1 = rotl32(x1, (r)); x1 ^= x0; }
  TF_ROUND(13) TF_ROUND(15) TF_ROUND(26) TF_ROUND(6)
  x0 += ks1; x1 += ks2 + 1u;
  TF_ROUND(17) TF_ROUND(29) TF_ROUND(16) TF_ROUND(24)
  x0 += ks2; x1 += ks0 + 2u;
  TF_ROUND(13) TF_ROUND(15) TF_ROUND(26) TF_ROUND(6)
  x0 += ks0; x1 += ks1 + 3u;
  TF_ROUND(17) TF_ROUND(29) TF_ROUND(16) TF_ROUND(24)
  x0 += ks1; x1 += ks2 + 4u;
  TF_ROUND(13) TF_ROUND(15) TF_ROUND(26) TF_ROUND(6)
  x0 += ks2; x1 += ks0 + 5u;
#undef TF_ROUND
  o0 = x0; o1 = x1;
}
__device__ __forceinline__ uint32_t random_bits32_partitionable(uint32_t k0, uint32_t k1,
                                                               uint32_t j) {
  uint32_t o0, o1;
  threefry2x32(k0, k1, 0u, j, o0, o1);
  return o0 ^ o1;
}

// ---------------- XLA ErfInv (f32 Giles polynomial) ----------------
__device__ __forceinline__ float erfinv_f32(float x) {
  float w = -log1pf(-(x * x));
  float p;
  if (w < 5.0f) {
    w = w - 2.5f;
    p = 2.81022636e-08f;
    p = fmaf(p, w, 3.43273939e-07f);
    p = fmaf(p, w, -3.5233877e-06f);
    p = fmaf(p, w, -4.39150654e-06f);
    p = fmaf(p, w, 0.00021858087f);
    p = fmaf(p, w, -0.00125372503f);
    p = fmaf(p, w, -0.00417768164f);
    p = fmaf(p, w, 0.246640727f);
    p = fmaf(p, w, 1.50140941f);
  } else {
    w = sqrtf(w) - 3.0f;
    p = -0.000200214257f;
    p = fmaf(p, w, 0.000100950558f);
    p = fmaf(p, w, 0.00134934322f);
    p = fmaf(p, w, -0.00367342844f);
    p = fmaf(p, w, 0.00573950773f);
    p = fmaf(p, w, -0.0076224613f);
    p = fmaf(p, w, 0.00943887047f);
    p = fmaf(p, w, 1.00167406f);
    p = fmaf(p, w, 2.83297682f);
  }
  return p * x;
}
__device__ __forceinline__ float bits_to_normal(uint32_t bits) {
  float f = __uint_as_float((bits >> 9) | 0x3F800000u) - 1.0f;   // [0,1)
  float u = f * 2.0f + (-0.99999994f);
  u = fmaxf(-0.99999994f, u);
  return 1.41421356237309515f * erfinv_f32(u);   // sqrt(2) as f32
}

// mish(x) = x * t/(t+2), t = e^x (e^x + 2)
__device__ __forceinline__ float mish_f(float x) {
  float e = expf(fminf(x, 20.0f));
  float t = fmaf(e, e, 2.0f * e);
  return x * (t / (t + 2.0f));
}

// ---------------- precompute: tf_all[1000][16], coefs[5][1000], keys[1000][2] -----
__global__ __launch_bounds__(64)
void precompute_kernel(const float* __restrict__ w_t1, const float* __restrict__ b_t1,
                       const float* __restrict__ w_t2, const float* __restrict__ b_t2,
                       float* __restrict__ tf_all, float* __restrict__ coefs,
                       uint32_t* __restrict__ keys) {
  const int i = blockIdx.x;
  const int j = threadIdx.x;
  const float tv = (float)i;
  __shared__ float hid[32];
  const float CF = (float)(-1.3157629102823120);  // -log(10000)/7
  if (j < 32) {
    float acc = b_t1[j];
#pragma unroll
    for (int k = 0; k < 16; ++k) {
      int kf = (k < 8) ? k : (k - 8);
      float fr = expf((float)kf * CF);
      float ang = tv * fr;
      float te = (k < 8) ? sinf(ang) : cosf(ang);
      acc = fmaf(te, w_t1[k * 32 + j], acc);
    }
    hid[j] = mish_f(acc);
  }
  __syncthreads();
  if (j < 16) {
    float acc = b_t2[j];
#pragma unroll
    for (int k2 = 0; k2 < 32; ++k2) acc = fmaf(hid[k2], w_t2[k2 * 16 + j], acc);
    tf_all[i * TDIM + j] = acc;
  }
  if (j == 0) {
    double t = (double)(i + 1);
    double ac  = exp(-0.1 * t / 1000.0 - 4.95 * t * t / 1.0e6);
    double acp = (i == 0) ? 1.0
        : exp(-0.1 * (t - 1.0) / 1000.0 - 4.95 * (t - 1.0) * (t - 1.0) / 1.0e6);
    double alpha = exp(-0.1 / 1000.0 - 4.95 * (2.0 * t - 1.0) / 1.0e6);
    double beta = 1.0 - alpha;
    double sr   = sqrt(1.0 / ac);
    double srm1 = sqrt(1.0 / ac - 1.0);
    double c1 = beta * sqrt(acp) / (1.0 - ac);
    double c2 = (1.0 - acp) * sqrt(alpha) / (1.0 - ac);
    double pv = beta * (1.0 - acp) / (1.0 - ac);
    double lv = log(fmax(pv, 1.0e-20));
    coefs[0 * T_STEPS + i] = (float)sr;
    coefs[1 * T_STEPS + i] = (float)srm1;
    coefs[2 * T_STEPS + i] = (float)c1;
    coefs[3 * T_STEPS + i] = (float)c2;
    float lvf = (float)lv;
    coefs[4 * T_STEPS + i] = expf(0.5f * lvf);
    uint32_t o0, o1;
    threefry2x32(0u, 1u, 0u, (uint32_t)i, o0, o1);
    keys[2 * i]     = o0;
    keys[2 * i + 1] = o1;
  }
}

// -------- prep: MFMA B-fragment hi/lo layout + w0tf transpose ---------------------
__global__ __launch_bounds__(64)
void prep_frags(const float* __restrict__ w0, const float* __restrict__ w1,
                const float* __restrict__ w2, const float* __restrict__ wf,
                unsigned short* __restrict__ f0x, unsigned short* __restrict__ f0s,
                unsigned short* __restrict__ f1, unsigned short* __restrict__ f2,
                unsigned short* __restrict__ ff, float* __restrict__ w0tf) {
  const int bid = blockIdx.x;   // 0..355
  const int l = threadIdx.x;    // 0..63
  if (bid >= 352) {             // w0tf transpose
    int n = (bid - 352) * 64 + l;
#pragma unroll
    for (int c = 0; c < 16; ++c) w0tf[n * 16 + c] = w0[(32 + c) * HID + n];
    return;
  }
  const float* W; unsigned short* F; int NT, N, idx, rowoff, Kmax;
  if (bid < 16)       { W = w0; F = f0x; NT = 16; N = 256; idx = bid;       rowoff = 0;  Kmax = 32;  }
  else if (bid < 80)  { W = w0; F = f0s; NT = 16; N = 256; idx = bid - 16;  rowoff = 48; Kmax = 128; }
  else if (bid < 208) { W = w1; F = f1;  NT = 16; N = 256; idx = bid - 80;  rowoff = 0;  Kmax = 256; }
  else if (bid < 336) { W = w2; F = f2;  NT = 16; N = 256; idx = bid - 208; rowoff = 0;  Kmax = 256; }
  else                { W = wf; F = ff;  NT = 2;  N = 32;  idx = bid - 336; rowoff = 0;  Kmax = 256; }
  const int kt = idx / NT, nt = idx % NT;
  const int n = nt * 16 + (l & 15);
  const int kbase = kt * 32 + (l >> 4) * 8;
  unsigned short* dst = F + idx * 1024 + l * 8;
#pragma unroll
  for (int j = 0; j < 8; ++j) {
    int k = kbase + j;
    float v = (k < Kmax) ? W[(rowoff + k) * N + n] : 0.0f;
    unsigned short h = f2bf(v);
    dst[j]       = h;
    dst[512 + j] = f2bf(v - bf2f(h));
  }
}

// ---------------- persistent main kernel ------------------------------------------
// L0 = 1 kt over x only (state part in persistent sacc regs; tf part via per-lane
// 16-dot). F1 is loop-invariant: loaded ONCE into 32 named short8 registers.
// F2/ff stream per-kt from L2 inside their MFMA loops (baseline style), with a
// 1-kt named-register prefetch issued before the preceding barrier.
__global__ __launch_bounds__(512, 2)
void diffusion_main(const float* __restrict__ state, const float* __restrict__ x_init,
                    const float* __restrict__ b0, const float* __restrict__ b1,
                    const float* __restrict__ b2, const float* __restrict__ bf,
                    const unsigned short* __restrict__ f0x, const unsigned short* __restrict__ f0s,
                    const unsigned short* __restrict__ f1, const unsigned short* __restrict__ f2,
                    const unsigned short* __restrict__ ff,
                    const float* __restrict__ tf_all, const float* __restrict__ w0tf,
                    const float* __restrict__ coefs,
                    const uint32_t* __restrict__ keys, float* __restrict__ out) {
  __shared__ __align__(16) unsigned short a0h[16][KPX], a0l[16][KPX];
  __shared__ __align__(16) unsigned short aAh[16][KPH], aAl[16][KPH];
  __shared__ __align__(16) unsigned short aBh[16][KPH], aBl[16][KPH];
  __shared__ float s_x[16][ADIM];
  __shared__ float s_eps[16][33];

  const int tid = threadIdx.x;          // 0..511
  const int base = blockIdx.x * 8;
  const int l = tid & 63;               // lane
  const int w = tid >> 6;               // wave 0..7
  const int lrow = l & 15;
  const int quad = l >> 4;              // 0..3
  const int nt0 = 2 * w, nt1 = 2 * w + 1;

  // ---- stage x_init (16x32 = 512, one elem/thread) ----
  {
    int r = tid >> 5, d = tid & 31;
    int grow = (r < 8) ? (base + r) : (2048 + base + r - 8);
    float v = x_init[grow * ADIM + d];
    s_x[r][d] = v;
    unsigned short h = f2bf(v);
    a0h[r][d] = h; a0l[r][d] = f2bf(v - bf2f(h));
  }
  // ---- stage state into aA cols 0..127 (one-time) ----
  for (int idx = tid; idx < 16 * SDIM; idx += 512) {
    int r = idx >> 7, c = idx & 127;
    int grow = (r < 8) ? (base + r) : (2048 + base + r - 8);
    float v = state[grow * SDIM + c];
    unsigned short h = f2bf(v);
    aAh[r][c] = h; aAl[r][c] = f2bf(v - bf2f(h));
  }

  const float b0A = b0[nt0 * 16 + lrow], b0B = b0[nt1 * 16 + lrow];
  const float b1A = b1[nt0 * 16 + lrow], b1B = b1[nt1 * 16 + lrow];
  const float b2A = b2[nt0 * 16 + lrow], b2B = b2[nt1 * 16 + lrow];
  const float bfv = (w < 2) ? bf[w * 16 + lrow] : 0.0f;
  __syncthreads();

  // ---- one-time: sacc = state-part of layer0 (persistent f32 accumulators) ----
  f32x4 sacc0 = {0.f, 0.f, 0.f, 0.f}, sacc1 = {0.f, 0.f, 0.f, 0.f};
  {
    const unsigned short* aH = &aAh[0][0] + lrow * KPH + quad * 8;
    const unsigned short* aL = &aAl[0][0] + lrow * KPH + quad * 8;
#pragma unroll
    for (int kt = 0; kt < 4; ++kt) {
      short8 ah = *reinterpret_cast<const short8*>(aH + kt * 32);
      short8 al = *reinterpret_cast<const short8*>(aL + kt * 32);
      const unsigned short* p0 = f0s + (kt * 16 + nt0) * 1024 + l * 8;
      const unsigned short* p1 = f0s + (kt * 16 + nt1) * 1024 + l * 8;
      short8 bh0 = *reinterpret_cast<const short8*>(p0);
      short8 bl0 = *reinterpret_cast<const short8*>(p0 + 512);
      short8 bh1 = *reinterpret_cast<const short8*>(p1);
      short8 bl1 = *reinterpret_cast<const short8*>(p1 + 512);
      sacc0 = MFMA(ah, bh0, sacc0); sacc1 = MFMA(ah, bh1, sacc1);
      sacc0 = MFMA(al, bh0, sacc0); sacc1 = MFMA(al, bh1, sacc1);
      sacc0 = MFMA(ah, bl0, sacc0); sacc1 = MFMA(ah, bl1, sacc1);
    }
  }

  // ---- persistent loop-invariant x fragments (kt=0 of layer0) ----
  short8 X0h, X0l, X1h, X1l;
  {
    const unsigned short* p0 = f0x + nt0 * 1024 + l * 8;
    const unsigned short* p1 = f0x + nt1 * 1024 + l * 8;
    X0h = *reinterpret_cast<const short8*>(p0);
    X0l = *reinterpret_cast<const short8*>(p0 + 512);
    X1h = *reinterpret_cast<const short8*>(p1);
    X1l = *reinterpret_cast<const short8*>(p1 + 512);
  }

  // ---- F1 loop-invariant: 32 NAMED short8 registers, loaded once ----
#define DECL_F1(k) short8 F1h0_##k, F1l0_##k, F1h1_##k, F1l1_##k;
  DECL_F1(0) DECL_F1(1) DECL_F1(2) DECL_F1(3)
  DECL_F1(4) DECL_F1(5) DECL_F1(6) DECL_F1(7)
#define LOAD_F1(k) { \
    const unsigned short* p0 = f1 + ((k) * 16 + nt0) * 1024 + l * 8; \
    const unsigned short* p1 = f1 + ((k) * 16 + nt1) * 1024 + l * 8; \
    F1h0_##k = *reinterpret_cast<const short8*>(p0); \
    F1l0_##k = *reinterpret_cast<const short8*>(p0 + 512); \
    F1h1_##k = *reinterpret_cast<const short8*>(p1); \
    F1l1_##k = *reinterpret_cast<const short8*>(p1 + 512); }
  LOAD_F1(0) LOAD_F1(1) LOAD_F1(2) LOAD_F1(3)
  LOAD_F1(4) LOAD_F1(5) LOAD_F1(6) LOAD_F1(7)

  // ---- per-lane tf-bias dot (wt vectors reloaded per call; L2-hot) ----
  const float* wtA_p = w0tf + (nt0 * 16 + lrow) * 16;
  const float* wtB_p = w0tf + (nt1 * 16 + lrow) * 16;
  float btA, btB;
  auto compute_bt = [&](int tt) {
    const float4* tfr = reinterpret_cast<const float4*>(tf_all + tt * TDIM);
    const float4* wA = reinterpret_cast<const float4*>(wtA_p);
    const float4* wB = reinterpret_cast<const float4*>(wtB_p);
    float a = 0.0f, b = 0.0f;
#pragma unroll
    for (int q = 0; q < 4; ++q) {
      float4 tq = tfr[q];
      float4 wa = wA[q], wb = wB[q];
      a = fmaf(tq.x, wa.x, a); b = fmaf(tq.x, wb.x, b);
      a = fmaf(tq.y, wa.y, a); b = fmaf(tq.y, wb.y, b);
      a = fmaf(tq.z, wa.z, a); b = fmaf(tq.z, wb.z, b);
      a = fmaf(tq.w, wa.w, a); b = fmaf(tq.w, wb.w, b);
    }
    btA = a; btB = b;
  };
  compute_bt(T_STEPS - 1);

  // epilogue helper: acc -> mish -> hi/lo LDS tile (captures scalars/LDS only)
  auto epi_store = [&](const f32x4& acc0, const f32x4& acc1, float bA, float bB,
                       unsigned short* dH, unsigned short* dL) {
#pragma unroll
    for (int reg = 0; reg < 4; ++reg) {
      int orow = quad * 4 + reg;
      float v0 = mish_f(acc0[reg] + bA);
      float v1 = mish_f(acc1[reg] + bB);
      unsigned short h0 = f2bf(v0), h1 = f2bf(v1);
      dH[orow * KPH + nt0 * 16 + lrow] = h0;
      dL[orow * KPH + nt0 * 16 + lrow] = f2bf(v0 - bf2f(h0));
      dH[orow * KPH + nt1 * 16 + lrow] = h1;
      dL[orow * KPH + nt1 * 16 + lrow] = f2bf(v1 - bf2f(h1));
    }
  };

  __syncthreads();  // B0

  for (int t = T_STEPS - 1; t >= 0; --t) {
    // uniform scalar loads for posterior (hidden under L0..LF)
    float sr  = coefs[0 * T_STEPS + t];
    float srm = coefs[1 * T_STEPS + t];
    float c1  = coefs[2 * T_STEPS + t];
    float c2  = coefs[3 * T_STEPS + t];
    float sig = (t != 0) ? coefs[4 * T_STEPS + t] : 0.0f;
    uint32_t k0 = keys[2 * t], k1 = keys[2 * t + 1];

    // ---- L0: x-part only (1 kt), acc starts from persistent state part ----
    {
      f32x4 acc0 = sacc0, acc1 = sacc1;
      short8 ah = *reinterpret_cast<const short8*>(&a0h[0][0] + lrow * KPX + quad * 8);
      short8 al = *reinterpret_cast<const short8*>(&a0l[0][0] + lrow * KPX + quad * 8);
      acc0 = MFMA(ah, X0h, acc0); acc1 = MFMA(ah, X1h, acc1);
      acc0 = MFMA(al, X0h, acc0); acc1 = MFMA(al, X1h, acc1);
      acc0 = MFMA(ah, X0l, acc0); acc1 = MFMA(ah, X1l, acc1);
      epi_store(acc0, acc1, b0A + btA, b0B + btB, &aAh[0][0], &aAl[0][0]);
    }
    __syncthreads();  // B1: aA ready

    // ---- L1: pure compute from resident F1 regs; prefetch F2 kt0 before B2 ----
    short8 P2h0, P2l0, P2h1, P2l1;
    {
      f32x4 acc0 = {0.f, 0.f, 0.f, 0.f}, acc1 = {0.f, 0.f, 0.f, 0.f};
      const unsigned short* aH = &aAh[0][0] + lrow * KPH + quad * 8;
      const unsigned short* aL = &aAl[0][0] + lrow * KPH + quad * 8;
#define L1_STEP(k) { \
      short8 ah = *reinterpret_cast<const short8*>(aH + (k) * 32); \
      short8 al = *reinterpret_cast<const short8*>(aL + (k) * 32); \
      acc0 = MFMA(ah, F1h0_##k, acc0); acc1 = MFMA(ah, F1h1_##k, acc1); \
      acc0 = MFMA(al, F1h0_##k, acc0); acc1 = MFMA(al, F1h1_##k, acc1); \
      acc0 = MFMA(ah, F1l0_##k, acc0); acc1 = MFMA(ah, F1l1_##k, acc1); }
      L1_STEP(0) L1_STEP(1) L1_STEP(2) L1_STEP(3)
      L1_STEP(4) L1_STEP(5) L1_STEP(6) L1_STEP(7)
#undef L1_STEP
      // prefetch F2 kt=0 (drains across B2)
      {
        const unsigned short* p0 = f2 + nt0 * 1024 + l * 8;
        const unsigned short* p1 = f2 + nt1 * 1024 + l * 8;
        P2h0 = *reinterpret_cast<const short8*>(p0);
        P2l0 = *reinterpret_cast<const short8*>(p0 + 512);
        P2h1 = *reinterpret_cast<const short8*>(p1);
        P2l1 = *reinterpret_cast<const short8*>(p1 + 512);
      }
      epi_store(acc0, acc1, b1A, b1B, &aBh[0][0], &aBl[0][0]);
    }
    __syncthreads();  // B2: aB ready

    // ---- L2: per-kt F2 streaming (kt0 prefetched); prefetch ff kt0 before B3 ----
    short8 Pfh, Pfl;
    {
      f32x4 acc0 = {0.f, 0.f, 0.f, 0.f}, acc1 = {0.f, 0.f, 0.f, 0.f};
      const unsigned short* aH = &aBh[0][0] + lrow * KPH + quad * 8;
      const unsigned short* aL = &aBl[0][0] + lrow * KPH + quad * 8;
      {  // kt = 0 from prefetch
        short8 ah = *reinterpret_cast<const short8*>(aH);
        short8 al = *reinterpret_cast<const short8*>(aL);
        acc0 = MFMA(ah, P2h0, acc0); acc1 = MFMA(ah, P2h1, acc1);
        acc0 = MFMA(al, P2h0, acc0); acc1 = MFMA(al, P2h1, acc1);
        acc0 = MFMA(ah, P2l0, acc0); acc1 = MFMA(ah, P2l1, acc1);
      }
#pragma unroll
      for (int kt = 1; kt < 8; ++kt) {
        const unsigned short* p0 = f2 + (kt * 16 + nt0) * 1024 + l * 8;
        const unsigned short* p1 = f2 + (kt * 16 + nt1) * 1024 + l * 8;
        short8 bh0 = *reinterpret_cast<const short8*>(p0);
        short8 bl0 = *reinterpret_cast<const short8*>(p0 + 512);
        short8 bh1 = *reinterpret_cast<const short8*>(p1);
        short8 bl1 = *reinterpret_cast<const short8*>(p1 + 512);
        short8 ah = *reinterpret_cast<const short8*>(aH + kt * 32);
        short8 al = *reinterpret_cast<const short8*>(aL + kt * 32);
        acc0 = MFMA(ah, bh0, acc0); acc1 = MFMA(ah, bh1, acc1);
        acc0 = MFMA(al, bh0, acc0); acc1 = MFMA(al, bh1, acc1);
        acc0 = MFMA(ah, bl0, acc0); acc1 = MFMA(ah, bl1, acc1);
      }
      // prefetch ff kt=0 (waves 0,1; drains across B3)
      if (w < 2) {
        const unsigned short* p = ff + w * 1024 + l * 8;
        Pfh = *reinterpret_cast<const short8*>(p);
        Pfl = *reinterpret_cast<const short8*>(p + 512);
      }
      epi_store(acc0, acc1, b2A, b2B, &aAh[0][0], &aAl[0][0]);
    }
    __syncthreads();  // B3: aA(L2 out) ready

    // ---- LF: 256->32, waves 0,1; per-kt ff streaming (kt0 prefetched) ----
    if (w < 2) {
      f32x4 acc = {0.f, 0.f, 0.f, 0.f};
      const unsigned short* aH = &aAh[0][0] + lrow * KPH + quad * 8;
      const unsigned short* aL = &aAl[0][0] + lrow * KPH + quad * 8;
      {  // kt = 0
        short8 ah = *reinterpret_cast<const short8*>(aH);
        short8 al = *reinterpret_cast<const short8*>(aL);
        acc = MFMA(ah, Pfh, acc);
        acc = MFMA(al, Pfh, acc);
        acc = MFMA(ah, Pfl, acc);
      }
#pragma unroll
      for (int kt = 1; kt < 8; ++kt) {
        const unsigned short* p = ff + (kt * 2 + w) * 1024 + l * 8;
        short8 bh = *reinterpret_cast<const short8*>(p);
        short8 bl = *reinterpret_cast<const short8*>(p + 512);
        short8 ah = *reinterpret_cast<const short8*>(aH + kt * 32);
        short8 al = *reinterpret_cast<const short8*>(aL + kt * 32);
        acc = MFMA(ah, bh, acc);
        acc = MFMA(al, bh, acc);
        acc = MFMA(ah, bl, acc);
      }
#pragma unroll
      for (int reg = 0; reg < 4; ++reg)
        s_eps[quad * 4 + reg][w * 16 + lrow] = acc[reg] + bfv;
    }
    __syncthreads();  // B4: eps ready

    // ---- posterior update + JAX noise; refresh a0 x tile ----
    {
      int d = tid & 31;
      int r = tid >> 5;
      int grow = (r < 8) ? (base + r) : (2048 + base + r - 8);
      uint32_t jflat = (uint32_t)(grow * ADIM + d);
      float nzv = bits_to_normal(random_bits32_partitionable(k0, k1, jflat));
      float xv = s_x[r][d];
      float eps = s_eps[r][d];
      float x0v = fminf(fmaxf(sr * xv - srm * eps, -1.0f), 1.0f);
      float xn = c1 * x0v + c2 * xv + sig * nzv;
      s_x[r][d] = xn;
      unsigned short h = f2bf(xn);
      a0h[r][d] = h; a0l[r][d] = f2bf(xn - bf2f(h));
    }
    // next iteration's tf-bias (hidden under posterior; drains at B5)
    compute_bt((t > 0) ? (t - 1) : 0);
    __syncthreads();  // B5: a0 ready for next L0
  }

  // ---- output (same thread wrote s_x[r][d]) ----
  {
    int r = tid >> 5, d = tid & 31;
    int grow = (r < 8) ? (base + r) : (2048 + base + r - 8);
    out[grow * ADIM + d] = fminf(fmaxf(s_x[r][d], -1.0f), 1.0f);
  }
}

// ---------------- launcher ----------------
extern "C" void kernel_launch(void* const* d_in, const int* in_sizes, int n_in,
                              void* d_out, int out_size, void* d_ws, size_t ws_size,
                              hipStream_t stream) {
  const float* state = (const float*)d_in[0];
  const float* x_init = (const float*)d_in[1];
  const float* w_t1 = (const float*)d_in[2];
  const float* b_t1 = (const float*)d_in[3];
  const float* w_t2 = (const float*)d_in[4];
  const float* b_t2 = (const float*)d_in[5];
  const float* w0 = (const float*)d_in[6];
  const float* b0 = (const float*)d_in[7];
  const float* w1 = (const float*)d_in[8];
  const float* b1 = (const float*)d_in[9];
  const float* w2 = (const float*)d_in[10];
  const float* b2 = (const float*)d_in[11];
  const float* wf = (const float*)d_in[12];
  const float* bf = (const float*)d_in[13];
  float* out = (float*)d_out;

  // ws layout (f32 units unless noted), total ~829 KB:
  //   tf_all[16000] | w0tf[4096] | coefs[5000] | keys[2000] u32
  //   | f0x[16K ush] | f0s[64K] | f1[128K] | f2[128K] | ff[16K]
  float* tf_all = (float*)d_ws;
  float* w0tf = tf_all + T_STEPS * TDIM;
  float* coefs = w0tf + HID * TDIM;
  uint32_t* keys = (uint32_t*)(coefs + 5 * T_STEPS);
  unsigned short* f0x = (unsigned short*)(keys + 2 * T_STEPS);
  unsigned short* f0s = f0x + 16 * 1024;
  unsigned short* f1 = f0s + 64 * 1024;
  unsigned short* f2 = f1 + 128 * 1024;
  unsigned short* ff = f2 + 128 * 1024;

  precompute_kernel<<<T_STEPS, 64, 0, stream>>>(w_t1, b_t1, w_t2, b_t2,
                                                tf_all, coefs, keys);
  prep_frags<<<356, 64, 0, stream>>>(w0, w1, w2, wf, f0x, f0s, f1, f2, ff, w0tf);
  diffusion_main<<<256, 512, 0, stream>>>(state, x_init, b0, b1, b2, bf,
                                          f0x, f0s, f1, f2, ff,
                                          tf_all, w0tf, coefs, keys, out);
}

// Round 5
// 15702.113 us; speedup vs baseline: 2.1842x; 1.2301x over previous
//
#include <hip/hip_runtime.h>
#include <stdint.h>

// ---------------- constants ----------------
#define T_STEPS 1000
#define SDIM    128
#define ADIM    32
#define HID     256
#define TDIM    16
#define KPX     40                     // padded K stride for x tile (32 used)
#define KPH     264                    // padded K stride for hidden tiles (256 used)

typedef __attribute__((ext_vector_type(8))) short short8;   // 8 bf16 (4 VGPRs)
typedef __attribute__((ext_vector_type(4))) float f32x4;    // MFMA accumulator

#define MFMA(A, B, C) __builtin_amdgcn_mfma_f32_16x16x32_bf16((A), (B), (C), 0, 0, 0)

// ---------------- bf16 helpers (RNE) ----------------
__device__ __forceinline__ unsigned short f2bf(float f) {
  uint32_t u = __float_as_uint(f);
  u = u + 0x7FFFu + ((u >> 16) & 1u);
  return (unsigned short)(u >> 16);
}
__device__ __forceinline__ float bf2f(unsigned short h) {
  return __uint_as_float(((uint32_t)h) << 16);
}

// ---------------- threefry2x32 (exact JAX semantics) ----------------
__device__ __forceinline__ uint32_t rotl32(uint32_t v, int d) {
  return (v << d) | (v >> (32 - d));
}
__device__ __forceinline__ void threefry2x32(uint32_t k0, uint32_t k1,
                                             uint32_t x0, uint32_t x1,
                                             uint32_t& o0, uint32_t& o1) {
  uint32_t ks0 = k0, ks1 = k1, ks2 = k0 ^ k1 ^ 0x1BD11BDAu;
  x0 += ks0; x1 += ks1;
#define TF_ROUND(r) { x0 += x1; x1 = rotl32(x1, (r)); x1 ^= x0; }
  TF_ROUND(13) TF_ROUND(15) TF_ROUND(26) TF_ROUND(6)
  x0 += ks1; x1 += ks2 + 1u;
  TF_ROUND(17) TF_ROUND(29) TF_ROUND(16) TF_ROUND(24)
  x0 += ks2; x1 += ks0 + 2u;
  TF_ROUND(13) TF_ROUND(15) TF_ROUND(26) TF_ROUND(6)
  x0 += ks0; x1 += ks1 + 3u;
  TF_ROUND(17) TF_ROUND(29) TF_ROUND(16) TF_ROUND(24)
  x0 += ks1; x1 += ks2 + 4u;
  TF_ROUND(13) TF_ROUND(15) TF_ROUND(26) TF_ROUND(6)
  x0 += ks2; x1 += ks0 + 5u;
#undef TF_ROUND
  o0 = x0; o1 = x1;
}
__device__ __forceinline__ uint32_t random_bits32_partitionable(uint32_t k0, uint32_t k1,
                                                               uint32_t j) {
  uint32_t o0, o1;
  threefry2x32(k0, k1, 0u, j, o0, o1);
  return o0 ^ o1;
}

// ---------------- XLA ErfInv (f32 Giles polynomial) ----------------
__device__ __forceinline__ float erfinv_f32(float x) {
  float w = -log1pf(-(x * x));
  float p;
  if (w < 5.0f) {
    w = w - 2.5f;
    p = 2.81022636e-08f;
    p = fmaf(p, w, 3.43273939e-07f);
    p = fmaf(p, w, -3.5233877e-06f);
    p = fmaf(p, w, -4.39150654e-06f);
    p = fmaf(p, w, 0.00021858087f);
    p = fmaf(p, w, -0.00125372503f);
    p = fmaf(p, w, -0.00417768164f);
    p = fmaf(p, w, 0.246640727f);
    p = fmaf(p, w, 1.50140941f);
  } else {
    w = sqrtf(w) - 3.0f;
    p = -0.000200214257f;
    p = fmaf(p, w, 0.000100950558f);
    p = fmaf(p, w, 0.00134934322f);
    p = fmaf(p, w, -0.00367342844f);
    p = fmaf(p, w, 0.00573950773f);
    p = fmaf(p, w, -0.0076224613f);
    p = fmaf(p, w, 0.00943887047f);
    p = fmaf(p, w, 1.00167406f);
    p = fmaf(p, w, 2.83297682f);
  }
  return p * x;
}
__device__ __forceinline__ float bits_to_normal(uint32_t bits) {
  float f = __uint_as_float((bits >> 9) | 0x3F800000u) - 1.0f;   // [0,1)
  float u = f * 2.0f + (-0.99999994f);
  u = fmaxf(-0.99999994f, u);
  return 1.41421356237309515f * erfinv_f32(u);   // sqrt(2) as f32
}

// mish(x) = x * t/(t+2), t = e^x (e^x + 2)
__device__ __forceinline__ float mish_f(float x) {
  float e = expf(fminf(x, 20.0f));
  float t = fmaf(e, e, 2.0f * e);
  return x * (t / (t + 2.0f));
}

// ---------------- precompute: tf_all[1000][16], coefs[5][1000], keys[1000][2] -----
__global__ __launch_bounds__(64)
void precompute_kernel(const float* __restrict__ w_t1, const float* __restrict__ b_t1,
                       const float* __restrict__ w_t2, const float* __restrict__ b_t2,
                       float* __restrict__ tf_all, float* __restrict__ coefs,
                       uint32_t* __restrict__ keys) {
  const int i = blockIdx.x;
  const int j = threadIdx.x;
  const float tv = (float)i;
  __shared__ float hid[32];
  const float CF = (float)(-1.3157629102823120);  // -log(10000)/7
  if (j < 32) {
    float acc = b_t1[j];
#pragma unroll
    for (int k = 0; k < 16; ++k) {
      int kf = (k < 8) ? k : (k - 8);
      float fr = expf((float)kf * CF);
      float ang = tv * fr;
      float te = (k < 8) ? sinf(ang) : cosf(ang);
      acc = fmaf(te, w_t1[k * 32 + j], acc);
    }
    hid[j] = mish_f(acc);
  }
  __syncthreads();
  if (j < 16) {
    float acc = b_t2[j];
#pragma unroll
    for (int k2 = 0; k2 < 32; ++k2) acc = fmaf(hid[k2], w_t2[k2 * 16 + j], acc);
    tf_all[i * TDIM + j] = acc;
  }
  if (j == 0) {
    double t = (double)(i + 1);
    double ac  = exp(-0.1 * t / 1000.0 - 4.95 * t * t / 1.0e6);
    double acp = (i == 0) ? 1.0
        : exp(-0.1 * (t - 1.0) / 1000.0 - 4.95 * (t - 1.0) * (t - 1.0) / 1.0e6);
    double alpha = exp(-0.1 / 1000.0 - 4.95 * (2.0 * t - 1.0) / 1.0e6);
    double beta = 1.0 - alpha;
    double sr   = sqrt(1.0 / ac);
    double srm1 = sqrt(1.0 / ac - 1.0);
    double c1 = beta * sqrt(acp) / (1.0 - ac);
    double c2 = (1.0 - acp) * sqrt(alpha) / (1.0 - ac);
    double pv = beta * (1.0 - acp) / (1.0 - ac);
    double lv = log(fmax(pv, 1.0e-20));
    coefs[0 * T_STEPS + i] = (float)sr;
    coefs[1 * T_STEPS + i] = (float)srm1;
    coefs[2 * T_STEPS + i] = (float)c1;
    coefs[3 * T_STEPS + i] = (float)c2;
    float lvf = (float)lv;
    coefs[4 * T_STEPS + i] = expf(0.5f * lvf);
    uint32_t o0, o1;
    threefry2x32(0u, 1u, 0u, (uint32_t)i, o0, o1);
    keys[2 * i]     = o0;
    keys[2 * i + 1] = o1;
  }
}

// -------- prep: MFMA B-fragment hi/lo layout + w0tf transpose ---------------------
__global__ __launch_bounds__(64)
void prep_frags(const float* __restrict__ w0, const float* __restrict__ w1,
                const float* __restrict__ w2, const float* __restrict__ wf,
                unsigned short* __restrict__ f0x, unsigned short* __restrict__ f0s,
                unsigned short* __restrict__ f1, unsigned short* __restrict__ f2,
                unsigned short* __restrict__ ff, float* __restrict__ w0tf) {
  const int bid = blockIdx.x;   // 0..355
  const int l = threadIdx.x;    // 0..63
  if (bid >= 352) {             // w0tf transpose
    int n = (bid - 352) * 64 + l;
#pragma unroll
    for (int c = 0; c < 16; ++c) w0tf[n * 16 + c] = w0[(32 + c) * HID + n];
    return;
  }
  const float* W; unsigned short* F; int NT, N, idx, rowoff, Kmax;
  if (bid < 16)       { W = w0; F = f0x; NT = 16; N = 256; idx = bid;       rowoff = 0;  Kmax = 32;  }
  else if (bid < 80)  { W = w0; F = f0s; NT = 16; N = 256; idx = bid - 16;  rowoff = 48; Kmax = 128; }
  else if (bid < 208) { W = w1; F = f1;  NT = 16; N = 256; idx = bid - 80;  rowoff = 0;  Kmax = 256; }
  else if (bid < 336) { W = w2; F = f2;  NT = 16; N = 256; idx = bid - 208; rowoff = 0;  Kmax = 256; }
  else                { W = wf; F = ff;  NT = 2;  N = 32;  idx = bid - 336; rowoff = 0;  Kmax = 256; }
  const int kt = idx / NT, nt = idx % NT;
  const int n = nt * 16 + (l & 15);
  const int kbase = kt * 32 + (l >> 4) * 8;
  unsigned short* dst = F + idx * 1024 + l * 8;
#pragma unroll
  for (int j = 0; j < 8; ++j) {
    int k = kbase + j;
    float v = (k < Kmax) ? W[(rowoff + k) * N + n] : 0.0f;
    unsigned short h = f2bf(v);
    dst[j]       = h;
    dst[512 + j] = f2bf(v - bf2f(h));
  }
}

// ---------------- persistent main kernel ------------------------------------------
// 16 waves (1024 threads) per block; wave w owns nt-column w (16 outputs) for
// L0/L1/L2. F1 slice = 64 VGPR/wave (residency plausible under the forced 128
// cap); F2 streamed per-kt; ff LDS-resident. 4 waves/SIMD occupancy hides the
// remaining stream latency via TLP.
__global__ __launch_bounds__(1024)
void diffusion_main(const float* __restrict__ state, const float* __restrict__ x_init,
                    const float* __restrict__ b0, const float* __restrict__ b1,
                    const float* __restrict__ b2, const float* __restrict__ bf,
                    const unsigned short* __restrict__ f0x, const unsigned short* __restrict__ f0s,
                    const unsigned short* __restrict__ f1, const unsigned short* __restrict__ f2,
                    const unsigned short* __restrict__ ff,
                    const float* __restrict__ tf_all, const float* __restrict__ w0tf,
                    const float* __restrict__ coefs,
                    const uint32_t* __restrict__ keys, float* __restrict__ out) {
  __shared__ __align__(16) unsigned short a0h[16][KPX], a0l[16][KPX];
  __shared__ __align__(16) unsigned short aAh[16][KPH], aAl[16][KPH];
  __shared__ __align__(16) unsigned short aBh[16][KPH], aBl[16][KPH];
  __shared__ __align__(16) unsigned short ffl[16 * 1024];   // ff resident (32 KB)
  __shared__ float s_x[16][ADIM];
  __shared__ float s_eps[16][33];

  const int tid = threadIdx.x;          // 0..1023
  const int base = blockIdx.x * 8;
  const int l = tid & 63;               // lane
  const int w = tid >> 6;               // wave 0..15
  const int lrow = l & 15;
  const int quad = l >> 4;              // 0..3
  const int nt = w;                     // one col-tile per wave

  // ---- stage x_init (16x32 = 512 elems; tid<512, same mapping as verified) ----
  if (tid < 512) {
    int r = tid >> 5, d = tid & 31;
    int grow = (r < 8) ? (base + r) : (2048 + base + r - 8);
    float v = x_init[grow * ADIM + d];
    s_x[r][d] = v;
    unsigned short h = f2bf(v);
    a0h[r][d] = h; a0l[r][d] = f2bf(v - bf2f(h));
  }
  // ---- stage state into aA cols 0..127 (one-time) ----
  for (int idx = tid; idx < 16 * SDIM; idx += 1024) {
    int r = idx >> 7, c = idx & 127;
    int grow = (r < 8) ? (base + r) : (2048 + base + r - 8);
    float v = state[grow * SDIM + c];
    unsigned short h = f2bf(v);
    aAh[r][c] = h; aAl[r][c] = f2bf(v - bf2f(h));
  }
  // ---- copy ff (32 KB) into LDS once ----
  {
    const int4* src = reinterpret_cast<const int4*>(ff);
    int4* dst = reinterpret_cast<int4*>(ffl);
    dst[tid] = src[tid];
    dst[tid + 1024] = src[tid + 1024];
  }

  const float b0v = b0[nt * 16 + lrow];
  const float b1v = b1[nt * 16 + lrow];
  const float b2v = b2[nt * 16 + lrow];
  const float bfv = (w < 2) ? bf[w * 16 + lrow] : 0.0f;
  __syncthreads();

  // ---- one-time: sacc = state-part of layer0 for this wave's nt ----
  f32x4 sacc = {0.f, 0.f, 0.f, 0.f};
  {
    const unsigned short* aH = &aAh[0][0] + lrow * KPH + quad * 8;
    const unsigned short* aL = &aAl[0][0] + lrow * KPH + quad * 8;
#pragma unroll
    for (int kt = 0; kt < 4; ++kt) {
      short8 ah = *reinterpret_cast<const short8*>(aH + kt * 32);
      short8 al = *reinterpret_cast<const short8*>(aL + kt * 32);
      const unsigned short* p = f0s + (kt * 16 + nt) * 1024 + l * 8;
      short8 bh = *reinterpret_cast<const short8*>(p);
      short8 bl = *reinterpret_cast<const short8*>(p + 512);
      sacc = MFMA(ah, bh, sacc);
      sacc = MFMA(al, bh, sacc);
      sacc = MFMA(ah, bl, sacc);
    }
  }

  // ---- persistent loop-invariant x fragments (kt=0 of layer0, this nt) ----
  short8 Xh, Xl;
  {
    const unsigned short* p = f0x + nt * 1024 + l * 8;
    Xh = *reinterpret_cast<const short8*>(p);
    Xl = *reinterpret_cast<const short8*>(p + 512);
  }

  // ---- F1 slice for this wave: 16 named short8 (64 VGPR), loaded once ----
#define DECL_F1(k) short8 F1h_##k, F1l_##k;
  DECL_F1(0) DECL_F1(1) DECL_F1(2) DECL_F1(3)
  DECL_F1(4) DECL_F1(5) DECL_F1(6) DECL_F1(7)
#define LOAD_F1(k) { \
    const unsigned short* p = f1 + ((k) * 16 + nt) * 1024 + l * 8; \
    F1h_##k = *reinterpret_cast<const short8*>(p); \
    F1l_##k = *reinterpret_cast<const short8*>(p + 512); }
  LOAD_F1(0) LOAD_F1(1) LOAD_F1(2) LOAD_F1(3)
  LOAD_F1(4) LOAD_F1(5) LOAD_F1(6) LOAD_F1(7)

  // ---- per-lane tf-bias dot (16 f32 FMAs; wt row re-read from L2 each call) ----
  float bt;
  auto compute_bt = [&](int tt) {
    const float4* tfr = reinterpret_cast<const float4*>(tf_all + tt * TDIM);
    const float4* wA = reinterpret_cast<const float4*>(w0tf + (nt * 16 + lrow) * 16);
    float a = 0.0f;
#pragma unroll
    for (int q = 0; q < 4; ++q) {
      float4 tq = tfr[q];
      float4 wa = wA[q];
      a = fmaf(tq.x, wa.x, a);
      a = fmaf(tq.y, wa.y, a);
      a = fmaf(tq.z, wa.z, a);
      a = fmaf(tq.w, wa.w, a);
    }
    bt = a;
  };
  compute_bt(T_STEPS - 1);

  // epilogue: acc -> mish -> hi/lo LDS tile (single nt column)
  auto epi_store = [&](const f32x4& acc, float bA,
                       unsigned short* dH, unsigned short* dL) {
#pragma unroll
    for (int reg = 0; reg < 4; ++reg) {
      int orow = quad * 4 + reg;
      float v = mish_f(acc[reg] + bA);
      unsigned short h = f2bf(v);
      dH[orow * KPH + nt * 16 + lrow] = h;
      dL[orow * KPH + nt * 16 + lrow] = f2bf(v - bf2f(h));
    }
  };

  __syncthreads();  // B0

  for (int t = T_STEPS - 1; t >= 0; --t) {
    float sr  = coefs[0 * T_STEPS + t];
    float srm = coefs[1 * T_STEPS + t];
    float c1  = coefs[2 * T_STEPS + t];
    float c2  = coefs[3 * T_STEPS + t];
    float sig = (t != 0) ? coefs[4 * T_STEPS + t] : 0.0f;
    uint32_t k0 = keys[2 * t], k1 = keys[2 * t + 1];

    // ---- L0: x-part only (1 kt), acc starts from persistent state part ----
    {
      f32x4 acc = sacc;
      short8 ah = *reinterpret_cast<const short8*>(&a0h[0][0] + lrow * KPX + quad * 8);
      short8 al = *reinterpret_cast<const short8*>(&a0l[0][0] + lrow * KPX + quad * 8);
      acc = MFMA(ah, Xh, acc);
      acc = MFMA(al, Xh, acc);
      acc = MFMA(ah, Xl, acc);
      epi_store(acc, b0v + bt, &aAh[0][0], &aAl[0][0]);
    }
    __syncthreads();  // B1: aA ready

    // ---- L1: compute from F1 regs; prefetch F2 kt0 before B2 ----
    short8 P2h, P2l;
    {
      f32x4 acc = {0.f, 0.f, 0.f, 0.f};
      const unsigned short* aH = &aAh[0][0] + lrow * KPH + quad * 8;
      const unsigned short* aL = &aAl[0][0] + lrow * KPH + quad * 8;
#define L1_STEP(k) { \
      short8 ah = *reinterpret_cast<const short8*>(aH + (k) * 32); \
      short8 al = *reinterpret_cast<const short8*>(aL + (k) * 32); \
      acc = MFMA(ah, F1h_##k, acc); \
      acc = MFMA(al, F1h_##k, acc); \
      acc = MFMA(ah, F1l_##k, acc); }
      L1_STEP(0) L1_STEP(1) L1_STEP(2) L1_STEP(3)
      L1_STEP(4) L1_STEP(5) L1_STEP(6) L1_STEP(7)
#undef L1_STEP
      {
        const unsigned short* p = f2 + nt * 1024 + l * 8;
        P2h = *reinterpret_cast<const short8*>(p);
        P2l = *reinterpret_cast<const short8*>(p + 512);
      }
      epi_store(acc, b1v, &aBh[0][0], &aBl[0][0]);
    }
    __syncthreads();  // B2: aB ready

    // ---- L2: per-kt F2 streaming (kt0 prefetched) ----
    {
      f32x4 acc = {0.f, 0.f, 0.f, 0.f};
      const unsigned short* aH = &aBh[0][0] + lrow * KPH + quad * 8;
      const unsigned short* aL = &aBl[0][0] + lrow * KPH + quad * 8;
      {  // kt = 0 from prefetch
        short8 ah = *reinterpret_cast<const short8*>(aH);
        short8 al = *reinterpret_cast<const short8*>(aL);
        acc = MFMA(ah, P2h, acc);
        acc = MFMA(al, P2h, acc);
        acc = MFMA(ah, P2l, acc);
      }
#pragma unroll
      for (int kt = 1; kt < 8; ++kt) {
        const unsigned short* p = f2 + (kt * 16 + nt) * 1024 + l * 8;
        short8 bh = *reinterpret_cast<const short8*>(p);
        short8 bl = *reinterpret_cast<const short8*>(p + 512);
        short8 ah = *reinterpret_cast<const short8*>(aH + kt * 32);
        short8 al = *reinterpret_cast<const short8*>(aL + kt * 32);
        acc = MFMA(ah, bh, acc);
        acc = MFMA(al, bh, acc);
        acc = MFMA(ah, bl, acc);
      }
      epi_store(acc, b2v, &aAh[0][0], &aAl[0][0]);
    }
    __syncthreads();  // B3: aA(L2 out) ready

    // ---- LF: 256->32, waves 0,1; ff from LDS ----
    if (w < 2) {
      f32x4 acc = {0.f, 0.f, 0.f, 0.f};
      const unsigned short* aH = &aAh[0][0] + lrow * KPH + quad * 8;
      const unsigned short* aL = &aAl[0][0] + lrow * KPH + quad * 8;
#pragma unroll
      for (int kt = 0; kt < 8; ++kt) {
        const unsigned short* p = &ffl[0] + (kt * 2 + w) * 1024 + l * 8;
        short8 bh = *reinterpret_cast<const short8*>(p);
        short8 bl = *reinterpret_cast<const short8*>(p + 512);
        short8 ah = *reinterpret_cast<const short8*>(aH + kt * 32);
        short8 al = *reinterpret_cast<const short8*>(aL + kt * 32);
        acc = MFMA(ah, bh, acc);
        acc = MFMA(al, bh, acc);
        acc = MFMA(ah, bl, acc);
      }
#pragma unroll
      for (int reg = 0; reg < 4; ++reg)
        s_eps[quad * 4 + reg][w * 16 + lrow] = acc[reg] + bfv;
    }
    __syncthreads();  // B4: eps ready

    // ---- posterior update + JAX noise; refresh a0 x tile (tid<512) ----
    if (tid < 512) {
      int d = tid & 31;
      int r = tid >> 5;
      int grow = (r < 8) ? (base + r) : (2048 + base + r - 8);
      uint32_t jflat = (uint32_t)(grow * ADIM + d);
      float nzv = bits_to_normal(random_bits32_partitionable(k0, k1, jflat));
      float xv = s_x[r][d];
      float eps = s_eps[r][d];
      float x0v = fminf(fmaxf(sr * xv - srm * eps, -1.0f), 1.0f);
      float xn = c1 * x0v + c2 * xv + sig * nzv;
      s_x[r][d] = xn;
      unsigned short h = f2bf(xn);
      a0h[r][d] = h; a0l[r][d] = f2bf(xn - bf2f(h));
    }
    // next iteration's tf-bias (all threads; hidden under posterior)
    compute_bt((t > 0) ? (t - 1) : 0);
    __syncthreads();  // B5: a0 ready for next L0
  }

  // ---- output ----
  if (tid < 512) {
    int r = tid >> 5, d = tid & 31;
    int grow = (r < 8) ? (base + r) : (2048 + base + r - 8);
    out[grow * ADIM + d] = fminf(fmaxf(s_x[r][d], -1.0f), 1.0f);
  }
}

// ---------------- launcher ----------------
extern "C" void kernel_launch(void* const* d_in, const int* in_sizes, int n_in,
                              void* d_out, int out_size, void* d_ws, size_t ws_size,
                              hipStream_t stream) {
  const float* state = (const float*)d_in[0];
  const float* x_init = (const float*)d_in[1];
  const float* w_t1 = (const float*)d_in[2];
  const float* b_t1 = (const float*)d_in[3];
  const float* w_t2 = (const float*)d_in[4];
  const float* b_t2 = (const float*)d_in[5];
  const float* w0 = (const float*)d_in[6];
  const float* b0 = (const float*)d_in[7];
  const float* w1 = (const float*)d_in[8];
  const float* b1 = (const float*)d_in[9];
  const float* w2 = (const float*)d_in[10];
  const float* b2 = (const float*)d_in[11];
  const float* wf = (const float*)d_in[12];
  const float* bf = (const float*)d_in[13];
  float* out = (float*)d_out;

  // ws layout (f32 units unless noted), total ~829 KB:
  //   tf_all[16000] | w0tf[4096] | coefs[5000] | keys[2000] u32
  //   | f0x[16K ush] | f0s[64K] | f1[128K] | f2[128K] | ff[16K]
  float* tf_all = (float*)d_ws;
  float* w0tf = tf_all + T_STEPS * TDIM;
  float* coefs = w0tf + HID * TDIM;
  uint32_t* keys = (uint32_t*)(coefs + 5 * T_STEPS);
  unsigned short* f0x = (unsigned short*)(keys + 2 * T_STEPS);
  unsigned short* f0s = f0x + 16 * 1024;
  unsigned short* f1 = f0s + 64 * 1024;
  unsigned short* f2 = f1 + 128 * 1024;
  unsigned short* ff = f2 + 128 * 1024;

  precompute_kernel<<<T_STEPS, 64, 0, stream>>>(w_t1, b_t1, w_t2, b_t2,
                                                tf_all, coefs, keys);
  prep_frags<<<356, 64, 0, stream>>>(w0, w1, w2, wf, f0x, f0s, f1, f2, ff, w0tf);
  diffusion_main<<<256, 1024, 0, stream>>>(state, x_init, b0, b1, b2, bf,
                                           f0x, f0s, f1, f2, ff,
                                           tf_all, w0tf, coefs, keys, out);
}